// Round 4
// baseline (1110.508 us; speedup 1.0000x reference)
//
#include <hip/hip_runtime.h>

#define DEV __device__ __forceinline__

// readlane: wave-uniform broadcast of lane `l`'s value (VALU pipe, no LDS)
DEV float rlane(float v, int l) {
  return __uint_as_float((unsigned)__builtin_amdgcn_readlane((int)__float_as_uint(v), l));
}

template <int CTRL>
DEV float dppf(float x, float old) {
  return __uint_as_float((unsigned)__builtin_amdgcn_update_dpp(
      (int)__float_as_uint(old), (int)__float_as_uint(x), CTRL, 0xF, 0xF, false));
}

// Full-wave (64-lane) reductions via DPP (VALU pipe). Result broadcast to all lanes.
// row_shr 1/2/4/8 builds per-16-row suffix sums; row_bcast:15 then :31 accumulate
// rows so lane 63 holds the full reduction (intermediate lanes are garbage; we
// only readlane(63)). Verified by hand: L63 = R3+R2 after bcast15, +R0+R1 after bcast31.
DEV float wave_sum(float x) {
  x += dppf<0x111>(x, 0.0f);   // row_shr:1
  x += dppf<0x112>(x, 0.0f);   // row_shr:2
  x += dppf<0x114>(x, 0.0f);   // row_shr:4
  x += dppf<0x118>(x, 0.0f);   // row_shr:8
  x += dppf<0x142>(x, 0.0f);   // row_bcast:15
  x += dppf<0x143>(x, 0.0f);   // row_bcast:31
  return rlane(x, 63);
}
DEV float wave_max(float x) {
  const float NI = -3.402823466e38f;
  x = fmaxf(x, dppf<0x111>(x, NI));
  x = fmaxf(x, dppf<0x112>(x, NI));
  x = fmaxf(x, dppf<0x114>(x, NI));
  x = fmaxf(x, dppf<0x118>(x, NI));
  x = fmaxf(x, dppf<0x142>(x, NI));
  x = fmaxf(x, dppf<0x143>(x, NI));
  return rlane(x, 63);
}

struct P {
  const float *pred, *prey, *obst, *act;
  const float *Wp, *bp, *Wy, *by, *Wob, *bob, *Wa, *ba;
  const float *Wq, *bq, *Wk, *bk, *Wv, *bv, *Wo, *bo;
  const float *W1, *b1, *W2, *b2, *W3, *b3;
  float *out;
};

// One batch element per block. 256 threads = 4 waves.
// lane = feature j (0..63). Wave w owns rows r = w + 4*i (i<16), wave 0 also row 64.
// Only query rows 0..4 matter for the output (reference slices out[:, :5]).
__global__ __launch_bounds__(256, 4) void gnn_critic_kernel(P p) {
  const int b = blockIdx.x;
  const int lane = threadIdx.x & 63;
  const int wid = threadIdx.x >> 6;

  // klds is XOR-swizzled: element (r, c) lives at klds[r][c ^ ((r&7)<<2)].
  // Writes: lane ^ wave-uniform const -> permutation, conflict-free.
  // Reads (lane = key row, float4 at c = h*16+4t): granule index mod 8 =
  // (4h+t) ^ (lane&7) -> exactly 8 lanes per bank-group -> conflict-free minimum.
  __shared__ float klds[65][64];
  __shared__ float vlds[65][64];     // v rows (column reads: consecutive lanes, 2/bank = free)
  __shared__ float pbuf[5][4][65];   // probs per (qrow, head, key); stride 65 -> heads on 4 banks

  // ---- hoisted per-feature weight columns ----
  const float wp0 = p.Wp[lane], wp1 = p.Wp[64 + lane], bpv = p.bp[lane];
  const float wy0 = p.Wy[lane], wy1 = p.Wy[64 + lane], byv = p.by[lane];
  const float wob0 = p.Wob[lane], wob1 = p.Wob[64 + lane], wob2 = p.Wob[128 + lane],
              bobv = p.bob[lane];
  const float wa0 = p.Wa[lane], wa1 = p.Wa[64 + lane], bav = p.ba[lane];
  const float wk64 = p.Wk[64 * 64 + lane], wk65 = p.Wk[65 * 64 + lane], bkv = p.bk[lane];
  const float wq64 = p.Wq[64 * 64 + lane], wq65 = p.Wq[65 * 64 + lane], bqv = p.bq[lane];
  const float bvv = p.bv[lane];

  float xr[17], kk[17], vv[17];
  float q0 = 0.f, q1 = 0.f;

  // ---- Phase A: entity embeddings (x rows stay in registers, lane = feature) ----
#pragma unroll
  for (int i = 0; i < 16; ++i) {
    const int r = wid + 4 * i;   // < 64 always
    float h, s0, s1;
    if (r < 5) {
      s0 = p.pred[(b * 5 + r) * 2 + 0];
      s1 = p.pred[(b * 5 + r) * 2 + 1];
      h = fmaxf(s0 * wp0 + s1 * wp1 + bpv, 0.f);
      const float a = p.act[b * 5 + r] * 3.14159265358979323846f;
      float sa, ca;
      sincosf(a, &sa, &ca);
      h += sa * wa0 + ca * wa1 + bav;
    } else if (r < 55) {
      const int m = r - 5;
      s0 = p.prey[(b * 50 + m) * 2 + 0];
      s1 = p.prey[(b * 50 + m) * 2 + 1];
      h = fmaxf(s0 * wy0 + s1 * wy1 + byv, 0.f);
    } else {
      const int m = r - 55;
      s0 = p.obst[(b * 10 + m) * 3 + 0];
      s1 = p.obst[(b * 10 + m) * 3 + 1];
      const float s2 = p.obst[(b * 10 + m) * 3 + 2];
      h = fmaxf(s0 * wob0 + s1 * wob1 + s2 * wob2 + bobv, 0.f);
    }
    xr[i] = h;
    kk[i] = bkv + s0 * wk64 + s1 * wk65;  // fold pos terms + bias into k acc
    vv[i] = bvv;
    if (i == 0) q0 = bqv + s0 * wq64 + s1 * wq65;              // qrow = wid
    if (i == 1 && wid == 0) q1 = bqv + s0 * wq64 + s1 * wq65;  // qrow 4 (wave 0)
  }
  if (wid == 0) {  // row 64 = obst #9
    const int m = 9;
    const float s0 = p.obst[(b * 10 + m) * 3 + 0];
    const float s1 = p.obst[(b * 10 + m) * 3 + 1];
    const float s2 = p.obst[(b * 10 + m) * 3 + 2];
    xr[16] = fmaxf(s0 * wob0 + s1 * wob1 + s2 * wob2 + bobv, 0.f);
    kk[16] = bkv + s0 * wk64 + s1 * wk65;
    vv[16] = bvv;
  }

  // ---- Phase B: k,v projections for all rows; q for rows 0..4.
  // readlane broadcasts x[r][c] (VALU), weights are coalesced vector loads.
  for (int c = 0; c < 64; ++c) {
    const float wk = p.Wk[c * 64 + lane];
    const float wv = p.Wv[c * 64 + lane];
    const float wq = p.Wq[c * 64 + lane];
#pragma unroll
    for (int i = 0; i < 16; ++i) {
      const float s = rlane(xr[i], c);
      kk[i] += s * wk;
      vv[i] += s * wv;
      if (i == 0) q0 += s * wq;
      if (i == 1) q1 += s * wq;  // garbage on waves 1..3, never used
    }
    if (wid == 0) {
      const float s = rlane(xr[16], c);
      kk[16] += s * wk;
      vv[16] += s * wv;
    }
  }

#pragma unroll
  for (int i = 0; i < 16; ++i) {
    const int r = wid + 4 * i;
    klds[r][lane ^ ((r & 7) << 2)] = kk[i];
    vlds[r][lane] = vv[i];
  }
  if (wid == 0) {
    klds[64][lane] = kk[16];   // (64&7)==0 -> no swizzle
    vlds[64][lane] = vv[16];
  }
  __syncthreads();

  // ---- Phase C: attention + out-proj + MLP for one query row ----
  auto attend = [&](float qv, int qr, float xself) {
    // logits & softmax: lane = key index m (0..63), key 64 handled uniformly
    const int sw = (lane & 7) << 2;  // inverse of the store swizzle for row=lane
#pragma unroll
    for (int h = 0; h < 4; ++h) {
      const float4 kA = *(const float4 *)&klds[lane][(h * 16 + 0) ^ sw];
      const float4 kB = *(const float4 *)&klds[lane][(h * 16 + 4) ^ sw];
      const float4 kC = *(const float4 *)&klds[lane][(h * 16 + 8) ^ sw];
      const float4 kD = *(const float4 *)&klds[lane][(h * 16 + 12) ^ sw];
      const float4 zA = *(const float4 *)&klds[64][h * 16 + 0];
      const float4 zB = *(const float4 *)&klds[64][h * 16 + 4];
      const float4 zC = *(const float4 *)&klds[64][h * 16 + 8];
      const float4 zD = *(const float4 *)&klds[64][h * 16 + 12];
      float l = 0.f, g = 0.f, sq;
      sq = rlane(qv, h * 16 + 0);  l += sq * kA.x; g += sq * zA.x;
      sq = rlane(qv, h * 16 + 1);  l += sq * kA.y; g += sq * zA.y;
      sq = rlane(qv, h * 16 + 2);  l += sq * kA.z; g += sq * zA.z;
      sq = rlane(qv, h * 16 + 3);  l += sq * kA.w; g += sq * zA.w;
      sq = rlane(qv, h * 16 + 4);  l += sq * kB.x; g += sq * zB.x;
      sq = rlane(qv, h * 16 + 5);  l += sq * kB.y; g += sq * zB.y;
      sq = rlane(qv, h * 16 + 6);  l += sq * kB.z; g += sq * zB.z;
      sq = rlane(qv, h * 16 + 7);  l += sq * kB.w; g += sq * zB.w;
      sq = rlane(qv, h * 16 + 8);  l += sq * kC.x; g += sq * zC.x;
      sq = rlane(qv, h * 16 + 9);  l += sq * kC.y; g += sq * zC.y;
      sq = rlane(qv, h * 16 + 10); l += sq * kC.z; g += sq * zC.z;
      sq = rlane(qv, h * 16 + 11); l += sq * kC.w; g += sq * zC.w;
      sq = rlane(qv, h * 16 + 12); l += sq * kD.x; g += sq * zD.x;
      sq = rlane(qv, h * 16 + 13); l += sq * kD.y; g += sq * zD.y;
      sq = rlane(qv, h * 16 + 14); l += sq * kD.z; g += sq * zD.z;
      sq = rlane(qv, h * 16 + 15); l += sq * kD.w; g += sq * zD.w;
      l *= 0.25f;  // 1/sqrt(dh=16)
      g *= 0.25f;
      const float mx = fmaxf(wave_max(l), g);
      const float e = __expf(l - mx);
      const float e64 = __expf(g - mx);
      const float s = wave_sum(e) + e64;
      const float inv = 1.0f / s;
      pbuf[qr][h][lane] = e * inv;
      if (lane == 0) pbuf[qr][h][64] = e64 * inv;
    }
    // ctx: lane = feature j again (same-wave LDS, no barrier needed)
    const int hh = lane >> 4;
    float ca = 0.f, cb = 0.f;
    for (int m = 0; m < 64; m += 2) {
      ca += pbuf[qr][hh][m] * vlds[m][lane];
      cb += pbuf[qr][hh][m + 1] * vlds[m + 1][lane];
    }
    ca += cb + pbuf[qr][hh][64] * vlds[64][lane];
    // out = x + ctx @ Wo + bo
    float o = xself + p.bo[lane], o2 = 0.f;
    for (int c = 0; c < 64; c += 2) {
      o += rlane(ca, c) * p.Wo[c * 64 + lane];
      o2 += rlane(ca, c + 1) * p.Wo[(c + 1) * 64 + lane];
    }
    o += o2;
    // MLP
    float h1 = p.b1[lane], h1b = 0.f;
    for (int c = 0; c < 64; c += 2) {
      h1 += rlane(o, c) * p.W1[c * 64 + lane];
      h1b += rlane(o, c + 1) * p.W1[(c + 1) * 64 + lane];
    }
    h1 = fmaxf(h1 + h1b, 0.f);
    float h2 = p.b2[lane], h2b = 0.f;
    for (int c = 0; c < 64; c += 2) {
      h2 += rlane(h1, c) * p.W2[c * 64 + lane];
      h2b += rlane(h1, c + 1) * p.W2[(c + 1) * 64 + lane];
    }
    h2 = fmaxf(h2 + h2b, 0.f);
    const float tot = wave_sum(h2 * p.W3[lane]);
    if (lane == 0) p.out[b * 5 + qr] = tot + p.b3[0];
  };

  attend(q0, wid, xr[0]);
  if (wid == 0) attend(q1, 4, xr[1]);
}

extern "C" void kernel_launch(void *const *d_in, const int *in_sizes, int n_in,
                              void *d_out, int out_size, void *d_ws, size_t ws_size,
                              hipStream_t stream) {
  P p;
  p.pred = (const float *)d_in[0];
  p.prey = (const float *)d_in[1];
  p.obst = (const float *)d_in[2];
  p.act  = (const float *)d_in[3];
  p.Wp = (const float *)d_in[4];  p.bp = (const float *)d_in[5];
  p.Wy = (const float *)d_in[6];  p.by = (const float *)d_in[7];
  p.Wob = (const float *)d_in[8]; p.bob = (const float *)d_in[9];
  p.Wa = (const float *)d_in[10]; p.ba = (const float *)d_in[11];
  p.Wq = (const float *)d_in[12]; p.bq = (const float *)d_in[13];
  p.Wk = (const float *)d_in[14]; p.bk = (const float *)d_in[15];
  p.Wv = (const float *)d_in[16]; p.bv = (const float *)d_in[17];
  p.Wo = (const float *)d_in[18]; p.bo = (const float *)d_in[19];
  p.W1 = (const float *)d_in[20]; p.b1 = (const float *)d_in[21];
  p.W2 = (const float *)d_in[22]; p.b2 = (const float *)d_in[23];
  p.W3 = (const float *)d_in[24]; p.b3 = (const float *)d_in[25];
  p.out = (float *)d_out;

  const int B = in_sizes[0] / 10;  // pred_state is (B, 5, 2)
  gnn_critic_kernel<<<dim3(B), dim3(256), 0, stream>>>(p);
}

// Round 5
// 963.711 us; speedup vs baseline: 1.1523x; 1.1523x over previous
//
#include <hip/hip_runtime.h>

#define DEV __device__ __forceinline__

// readlane: wave-uniform broadcast of lane `l`'s value (VALU pipe, no LDS)
DEV float rlane(float v, int l) {
  return __uint_as_float((unsigned)__builtin_amdgcn_readlane((int)__float_as_uint(v), l));
}

template <int CTRL>
DEV float dppf(float x, float old) {
  return __uint_as_float((unsigned)__builtin_amdgcn_update_dpp(
      (int)__float_as_uint(old), (int)__float_as_uint(x), CTRL, 0xF, 0xF, false));
}

// Full-wave (64-lane) reductions via DPP (VALU pipe). Result broadcast to all lanes.
// row_shr 1/2/4/8 builds per-16-row suffix sums; row_bcast:15 then :31 accumulate
// rows so lane 63 holds the full reduction (intermediate lanes are garbage; we
// only readlane(63)).
DEV float wave_sum(float x) {
  x += dppf<0x111>(x, 0.0f);   // row_shr:1
  x += dppf<0x112>(x, 0.0f);   // row_shr:2
  x += dppf<0x114>(x, 0.0f);   // row_shr:4
  x += dppf<0x118>(x, 0.0f);   // row_shr:8
  x += dppf<0x142>(x, 0.0f);   // row_bcast:15
  x += dppf<0x143>(x, 0.0f);   // row_bcast:31
  return rlane(x, 63);
}
DEV float wave_max(float x) {
  const float NI = -3.402823466e38f;
  x = fmaxf(x, dppf<0x111>(x, NI));
  x = fmaxf(x, dppf<0x112>(x, NI));
  x = fmaxf(x, dppf<0x114>(x, NI));
  x = fmaxf(x, dppf<0x118>(x, NI));
  x = fmaxf(x, dppf<0x142>(x, NI));
  x = fmaxf(x, dppf<0x143>(x, NI));
  return rlane(x, 63);
}

struct P {
  const float *pred, *prey, *obst, *act;
  const float *Wp, *bp, *Wy, *by, *Wob, *bob, *Wa, *ba;
  const float *Wq, *bq, *Wk, *bk, *Wv, *bv, *Wo, *bo;
  const float *W1, *b1, *W2, *b2, *W3, *b3;
  float *out;
};

// One batch element per block. 256 threads = 4 waves.
// lane = feature j (0..63). Wave w owns rows r = w + 4*i (i<16), wave 0 also row 64.
// Only query rows 0..4 matter for the output (reference slices out[:, :5]).
//
// Occupancy: LDS 38.9 KB/block caps at 4 blocks/CU (16 waves) regardless of VGPRs.
// R4 post-mortem: __launch_bounds__(256,4) let the allocator target the 64-VGPR /
// 8-wave bucket and spill ~2.2 GB/dispatch of accumulators to scratch (WRITE_SIZE
// 1.84 GB, dur 1085us). waves_per_eu(2,4) pins the occupancy target to what LDS
// allows, raising the VGPR budget so xr/kk/vv stay in registers.
__global__ void __launch_bounds__(256)
__attribute__((amdgpu_waves_per_eu(2, 4))) gnn_critic_kernel(P p) {
  const int b = blockIdx.x;
  const int lane = threadIdx.x & 63;
  const int wid = threadIdx.x >> 6;

  // klds is XOR-swizzled: element (r, c) lives at klds[r][c ^ ((r&7)<<2)].
  // Writes: lane ^ wave-uniform const -> permutation, conflict-free.
  // Reads (lane = key row, float4 at c = h*16+4t): granule index mod 8 =
  // (4h+t) ^ (lane&7) -> exactly 8 lanes per bank-group -> conflict-free minimum.
  __shared__ float klds[65][64];
  __shared__ float vlds[65][64];     // v rows (column reads: consecutive lanes, 2/bank = free)
  __shared__ float pbuf[5][4][65];   // probs per (qrow, head, key); stride 65 -> heads on 4 banks

  // ---- hoisted per-feature weight columns ----
  const float wp0 = p.Wp[lane], wp1 = p.Wp[64 + lane], bpv = p.bp[lane];
  const float wy0 = p.Wy[lane], wy1 = p.Wy[64 + lane], byv = p.by[lane];
  const float wob0 = p.Wob[lane], wob1 = p.Wob[64 + lane], wob2 = p.Wob[128 + lane],
              bobv = p.bob[lane];
  const float wa0 = p.Wa[lane], wa1 = p.Wa[64 + lane], bav = p.ba[lane];
  const float wk64 = p.Wk[64 * 64 + lane], wk65 = p.Wk[65 * 64 + lane], bkv = p.bk[lane];
  const float wq64 = p.Wq[64 * 64 + lane], wq65 = p.Wq[65 * 64 + lane], bqv = p.bq[lane];
  const float bvv = p.bv[lane];

  float xr[17], kk[17], vv[17];
  float q0 = 0.f, q1 = 0.f;

  // ---- Phase A: entity embeddings (x rows stay in registers, lane = feature) ----
#pragma unroll
  for (int i = 0; i < 16; ++i) {
    const int r = wid + 4 * i;   // < 64 always
    float h, s0, s1;
    if (r < 5) {
      s0 = p.pred[(b * 5 + r) * 2 + 0];
      s1 = p.pred[(b * 5 + r) * 2 + 1];
      h = fmaxf(s0 * wp0 + s1 * wp1 + bpv, 0.f);
      const float a = p.act[b * 5 + r] * 3.14159265358979323846f;
      float sa, ca;
      sincosf(a, &sa, &ca);
      h += sa * wa0 + ca * wa1 + bav;
    } else if (r < 55) {
      const int m = r - 5;
      s0 = p.prey[(b * 50 + m) * 2 + 0];
      s1 = p.prey[(b * 50 + m) * 2 + 1];
      h = fmaxf(s0 * wy0 + s1 * wy1 + byv, 0.f);
    } else {
      const int m = r - 55;
      s0 = p.obst[(b * 10 + m) * 3 + 0];
      s1 = p.obst[(b * 10 + m) * 3 + 1];
      const float s2 = p.obst[(b * 10 + m) * 3 + 2];
      h = fmaxf(s0 * wob0 + s1 * wob1 + s2 * wob2 + bobv, 0.f);
    }
    xr[i] = h;
    kk[i] = bkv + s0 * wk64 + s1 * wk65;  // fold pos terms + bias into k acc
    vv[i] = bvv;
    if (i == 0) q0 = bqv + s0 * wq64 + s1 * wq65;              // qrow = wid
    if (i == 1 && wid == 0) q1 = bqv + s0 * wq64 + s1 * wq65;  // qrow 4 (wave 0)
  }
  if (wid == 0) {  // row 64 = obst #9
    const int m = 9;
    const float s0 = p.obst[(b * 10 + m) * 3 + 0];
    const float s1 = p.obst[(b * 10 + m) * 3 + 1];
    const float s2 = p.obst[(b * 10 + m) * 3 + 2];
    xr[16] = fmaxf(s0 * wob0 + s1 * wob1 + s2 * wob2 + bobv, 0.f);
    kk[16] = bkv + s0 * wk64 + s1 * wk65;
    vv[16] = bvv;
  }

  // ---- Phase B: k,v projections for all rows; q for rows 0..4.
  // readlane broadcasts x[r][c] (VALU), weights are coalesced vector loads.
  for (int c = 0; c < 64; ++c) {
    const float wk = p.Wk[c * 64 + lane];
    const float wv = p.Wv[c * 64 + lane];
    const float wq = p.Wq[c * 64 + lane];
#pragma unroll
    for (int i = 0; i < 16; ++i) {
      const float s = rlane(xr[i], c);
      kk[i] += s * wk;
      vv[i] += s * wv;
      if (i == 0) q0 += s * wq;
      if (i == 1) q1 += s * wq;  // garbage on waves 1..3, never used
    }
    if (wid == 0) {
      const float s = rlane(xr[16], c);
      kk[16] += s * wk;
      vv[16] += s * wv;
    }
  }

#pragma unroll
  for (int i = 0; i < 16; ++i) {
    const int r = wid + 4 * i;
    klds[r][lane ^ ((r & 7) << 2)] = kk[i];
    vlds[r][lane] = vv[i];
  }
  if (wid == 0) {
    klds[64][lane] = kk[16];   // (64&7)==0 -> no swizzle
    vlds[64][lane] = vv[16];
  }
  __syncthreads();

  // ---- Phase C: attention + out-proj + MLP for one query row ----
  auto attend = [&](float qv, int qr, float xself) {
    // logits & softmax: lane = key index m (0..63), key 64 handled uniformly
    const int sw = (lane & 7) << 2;  // inverse of the store swizzle for row=lane
#pragma unroll
    for (int h = 0; h < 4; ++h) {
      const float4 kA = *(const float4 *)&klds[lane][(h * 16 + 0) ^ sw];
      const float4 kB = *(const float4 *)&klds[lane][(h * 16 + 4) ^ sw];
      const float4 kC = *(const float4 *)&klds[lane][(h * 16 + 8) ^ sw];
      const float4 kD = *(const float4 *)&klds[lane][(h * 16 + 12) ^ sw];
      const float4 zA = *(const float4 *)&klds[64][h * 16 + 0];
      const float4 zB = *(const float4 *)&klds[64][h * 16 + 4];
      const float4 zC = *(const float4 *)&klds[64][h * 16 + 8];
      const float4 zD = *(const float4 *)&klds[64][h * 16 + 12];
      float l = 0.f, g = 0.f, sq;
      sq = rlane(qv, h * 16 + 0);  l += sq * kA.x; g += sq * zA.x;
      sq = rlane(qv, h * 16 + 1);  l += sq * kA.y; g += sq * zA.y;
      sq = rlane(qv, h * 16 + 2);  l += sq * kA.z; g += sq * zA.z;
      sq = rlane(qv, h * 16 + 3);  l += sq * kA.w; g += sq * zA.w;
      sq = rlane(qv, h * 16 + 4);  l += sq * kB.x; g += sq * zB.x;
      sq = rlane(qv, h * 16 + 5);  l += sq * kB.y; g += sq * zB.y;
      sq = rlane(qv, h * 16 + 6);  l += sq * kB.z; g += sq * zB.z;
      sq = rlane(qv, h * 16 + 7);  l += sq * kB.w; g += sq * zB.w;
      sq = rlane(qv, h * 16 + 8);  l += sq * kC.x; g += sq * zC.x;
      sq = rlane(qv, h * 16 + 9);  l += sq * kC.y; g += sq * zC.y;
      sq = rlane(qv, h * 16 + 10); l += sq * kC.z; g += sq * zC.z;
      sq = rlane(qv, h * 16 + 11); l += sq * kC.w; g += sq * zC.w;
      sq = rlane(qv, h * 16 + 12); l += sq * kD.x; g += sq * zD.x;
      sq = rlane(qv, h * 16 + 13); l += sq * kD.y; g += sq * zD.y;
      sq = rlane(qv, h * 16 + 14); l += sq * kD.z; g += sq * zD.z;
      sq = rlane(qv, h * 16 + 15); l += sq * kD.w; g += sq * zD.w;
      l *= 0.25f;  // 1/sqrt(dh=16)
      g *= 0.25f;
      const float mx = fmaxf(wave_max(l), g);
      const float e = __expf(l - mx);
      const float e64 = __expf(g - mx);
      const float s = wave_sum(e) + e64;
      const float inv = 1.0f / s;
      pbuf[qr][h][lane] = e * inv;
      if (lane == 0) pbuf[qr][h][64] = e64 * inv;
    }
    // ctx: lane = feature j again (same-wave LDS, no barrier needed)
    const int hh = lane >> 4;
    float ca = 0.f, cb = 0.f;
    for (int m = 0; m < 64; m += 2) {
      ca += pbuf[qr][hh][m] * vlds[m][lane];
      cb += pbuf[qr][hh][m + 1] * vlds[m + 1][lane];
    }
    ca += cb + pbuf[qr][hh][64] * vlds[64][lane];
    // out = x + ctx @ Wo + bo
    float o = xself + p.bo[lane], o2 = 0.f;
    for (int c = 0; c < 64; c += 2) {
      o += rlane(ca, c) * p.Wo[c * 64 + lane];
      o2 += rlane(ca, c + 1) * p.Wo[(c + 1) * 64 + lane];
    }
    o += o2;
    // MLP
    float h1 = p.b1[lane], h1b = 0.f;
    for (int c = 0; c < 64; c += 2) {
      h1 += rlane(o, c) * p.W1[c * 64 + lane];
      h1b += rlane(o, c + 1) * p.W1[(c + 1) * 64 + lane];
    }
    h1 = fmaxf(h1 + h1b, 0.f);
    float h2 = p.b2[lane], h2b = 0.f;
    for (int c = 0; c < 64; c += 2) {
      h2 += rlane(h1, c) * p.W2[c * 64 + lane];
      h2b += rlane(h1, c + 1) * p.W2[(c + 1) * 64 + lane];
    }
    h2 = fmaxf(h2 + h2b, 0.f);
    const float tot = wave_sum(h2 * p.W3[lane]);
    if (lane == 0) p.out[b * 5 + qr] = tot + p.b3[0];
  };

  attend(q0, wid, xr[0]);
  if (wid == 0) attend(q1, 4, xr[1]);
}

extern "C" void kernel_launch(void *const *d_in, const int *in_sizes, int n_in,
                              void *d_out, int out_size, void *d_ws, size_t ws_size,
                              hipStream_t stream) {
  P p;
  p.pred = (const float *)d_in[0];
  p.prey = (const float *)d_in[1];
  p.obst = (const float *)d_in[2];
  p.act  = (const float *)d_in[3];
  p.Wp = (const float *)d_in[4];  p.bp = (const float *)d_in[5];
  p.Wy = (const float *)d_in[6];  p.by = (const float *)d_in[7];
  p.Wob = (const float *)d_in[8]; p.bob = (const float *)d_in[9];
  p.Wa = (const float *)d_in[10]; p.ba = (const float *)d_in[11];
  p.Wq = (const float *)d_in[12]; p.bq = (const float *)d_in[13];
  p.Wk = (const float *)d_in[14]; p.bk = (const float *)d_in[15];
  p.Wv = (const float *)d_in[16]; p.bv = (const float *)d_in[17];
  p.Wo = (const float *)d_in[18]; p.bo = (const float *)d_in[19];
  p.W1 = (const float *)d_in[20]; p.b1 = (const float *)d_in[21];
  p.W2 = (const float *)d_in[22]; p.b2 = (const float *)d_in[23];
  p.W3 = (const float *)d_in[24]; p.b3 = (const float *)d_in[25];
  p.out = (float *)d_out;

  const int B = in_sizes[0] / 10;  // pred_state is (B, 5, 2)
  gnn_critic_kernel<<<dim3(B), dim3(256), 0, stream>>>(p);
}

// Round 7
// 456.483 us; speedup vs baseline: 2.4327x; 2.1112x over previous
//
#include <hip/hip_runtime.h>

#define DEV __device__ __forceinline__

// readlane: wave-uniform broadcast of lane `l`'s value (VALU pipe, no LDS)
DEV float rlane(float v, int l) {
  return __uint_as_float((unsigned)__builtin_amdgcn_readlane((int)__float_as_uint(v), l));
}

template <int CTRL>
DEV float dppf(float x, float old) {
  return __uint_as_float((unsigned)__builtin_amdgcn_update_dpp(
      (int)__float_as_uint(old), (int)__float_as_uint(x), CTRL, 0xF, 0xF, false));
}

// Full-wave (64-lane) reductions via DPP (VALU pipe). Lane 63 holds the full
// reduction after row_shr 1/2/4/8 + row_bcast 15/31; readlane(63) broadcasts.
DEV float wave_sum(float x) {
  x += dppf<0x111>(x, 0.0f);   // row_shr:1
  x += dppf<0x112>(x, 0.0f);   // row_shr:2
  x += dppf<0x114>(x, 0.0f);   // row_shr:4
  x += dppf<0x118>(x, 0.0f);   // row_shr:8
  x += dppf<0x142>(x, 0.0f);   // row_bcast:15
  x += dppf<0x143>(x, 0.0f);   // row_bcast:31
  return rlane(x, 63);
}
DEV float wave_max(float x) {
  const float NI = -3.402823466e38f;
  x = fmaxf(x, dppf<0x111>(x, NI));
  x = fmaxf(x, dppf<0x112>(x, NI));
  x = fmaxf(x, dppf<0x114>(x, NI));
  x = fmaxf(x, dppf<0x118>(x, NI));
  x = fmaxf(x, dppf<0x142>(x, NI));
  x = fmaxf(x, dppf<0x143>(x, NI));
  return rlane(x, 63);
}

struct P {
  const float *pred, *prey, *obst, *act;
  const float *Wp, *bp, *Wy, *by, *Wob, *bob, *Wa, *ba;
  const float *Wq, *bq, *Wk, *bk, *Wv, *bv, *Wo, *bo;
  const float *W1, *b1, *W2, *b2, *W3, *b3;
  float *out;
};

// One batch element per block. 512 threads = 8 waves.
// lane = feature j (0..63). Wave w owns rows r = w + 8*i (i<8); wave 0 also row 64.
// Only query rows 0..4 matter (reference slices out[:, :5]); wave w<5 owns qrow w.
//
// R4/R5 post-mortem: 4-wave/17-rows-per-wave needed ~150 live VGPRs -> spilled
// at both the 64-reg (R4: 2.29 GB scratch traffic) and 128-reg (R5: 0.59 GB)
// budgets. 8 waves x 8 rows cuts accumulators to 27 regs so the 128 bucket
// fits spill-free, and doubles waves/block on the same 38.9 KB LDS.
// waves_per_eu(2,4) stops the allocator from re-targeting the 64-reg bucket.
__global__ void __launch_bounds__(512)
__attribute__((amdgpu_waves_per_eu(2, 4))) gnn_critic_kernel(P p) {
  const int b = blockIdx.x;
  const int lane = threadIdx.x & 63;
  const int wid = threadIdx.x >> 6;  // 0..7

  // klds XOR-swizzled: element (r, c) at klds[r][c ^ ((r&7)<<2)].
  // Writes: r&7 == wid (wave-uniform) -> lane ^ const = permutation, conflict-free.
  // Reads (lane = key row, float4 at c = h*16+4t): granule (4h+t)^(lane&7) mod 8
  // -> exactly 8 lanes per bank-group -> conflict-free minimum.
  __shared__ float klds[65][64];
  __shared__ float vlds[65][64];     // v rows (column reads: consecutive lanes, 2/bank = free)
  __shared__ float pbuf[5][4][65];   // probs per (qrow, head, key); stride 65 -> heads on 4 banks

  // ---- hoisted per-feature weight columns ----
  const float wp0 = p.Wp[lane], wp1 = p.Wp[64 + lane], bpv = p.bp[lane];
  const float wy0 = p.Wy[lane], wy1 = p.Wy[64 + lane], byv = p.by[lane];
  const float wob0 = p.Wob[lane], wob1 = p.Wob[64 + lane], wob2 = p.Wob[128 + lane],
              bobv = p.bob[lane];
  const float wa0 = p.Wa[lane], wa1 = p.Wa[64 + lane], bav = p.ba[lane];
  const float wk64 = p.Wk[64 * 64 + lane], wk65 = p.Wk[65 * 64 + lane], bkv = p.bk[lane];
  const float wq64 = p.Wq[64 * 64 + lane], wq65 = p.Wq[65 * 64 + lane], bqv = p.bq[lane];
  const float bvv = p.bv[lane];

  float xr[9], kk[9], vv[9];
  float q0 = 0.f;

  // ---- Phase A: entity embeddings (x rows stay in registers, lane = feature) ----
#pragma unroll
  for (int i = 0; i < 8; ++i) {
    const int r = wid + 8 * i;   // 0..63
    float h, s0, s1;
    if (r < 5) {                 // only i==0, waves 0..4 (wave-uniform branch)
      s0 = p.pred[(b * 5 + r) * 2 + 0];
      s1 = p.pred[(b * 5 + r) * 2 + 1];
      h = fmaxf(s0 * wp0 + s1 * wp1 + bpv, 0.f);
      const float a = p.act[b * 5 + r] * 3.14159265358979323846f;
      float sa, ca;
      sincosf(a, &sa, &ca);
      h += sa * wa0 + ca * wa1 + bav;
    } else if (r < 55) {
      const int m = r - 5;
      s0 = p.prey[(b * 50 + m) * 2 + 0];
      s1 = p.prey[(b * 50 + m) * 2 + 1];
      h = fmaxf(s0 * wy0 + s1 * wy1 + byv, 0.f);
    } else {
      const int m = r - 55;
      s0 = p.obst[(b * 10 + m) * 3 + 0];
      s1 = p.obst[(b * 10 + m) * 3 + 1];
      const float s2 = p.obst[(b * 10 + m) * 3 + 2];
      h = fmaxf(s0 * wob0 + s1 * wob1 + s2 * wob2 + bobv, 0.f);
    }
    xr[i] = h;
    kk[i] = bkv + s0 * wk64 + s1 * wk65;  // fold pos terms + bias into k acc
    vv[i] = bvv;
    if (i == 0) q0 = bqv + s0 * wq64 + s1 * wq65;  // qrow = wid (dead on waves 5..7)
  }
  if (wid == 0) {  // row 64 = obst #9
    const float s0 = p.obst[(b * 10 + 9) * 3 + 0];
    const float s1 = p.obst[(b * 10 + 9) * 3 + 1];
    const float s2 = p.obst[(b * 10 + 9) * 3 + 2];
    xr[8] = fmaxf(s0 * wob0 + s1 * wob1 + s2 * wob2 + bobv, 0.f);
    kk[8] = bkv + s0 * wk64 + s1 * wk65;
    vv[8] = bvv;
  }

  // ---- Phase B: k,v projections for all rows; q for this wave's row.
  // readlane broadcasts x[r][c] (VALU), weights are coalesced vector loads.
  for (int c = 0; c < 64; ++c) {
    const float wk = p.Wk[c * 64 + lane];
    const float wv = p.Wv[c * 64 + lane];
    const float wq = p.Wq[c * 64 + lane];
#pragma unroll
    for (int i = 0; i < 8; ++i) {
      const float s = rlane(xr[i], c);
      kk[i] += s * wk;
      vv[i] += s * wv;
      if (i == 0) q0 += s * wq;
    }
    if (wid == 0) {
      const float s = rlane(xr[8], c);
      kk[8] += s * wk;
      vv[8] += s * wv;
    }
  }

#pragma unroll
  for (int i = 0; i < 8; ++i) {
    const int r = wid + 8 * i;
    klds[r][lane ^ ((r & 7) << 2)] = kk[i];   // r&7 == wid
    vlds[r][lane] = vv[i];
  }
  if (wid == 0) {
    klds[64][lane] = kk[8];   // (64&7)==0 -> no swizzle
    vlds[64][lane] = vv[8];
  }
  __syncthreads();

  // ---- Phase C: attention + out-proj + MLP, one query row per wave (waves 0..4) ----
  auto attend = [&](float qv, int qr, float xself) {
    // logits & softmax: lane = key index m (0..63), key 64 handled uniformly
    const int sw = (lane & 7) << 2;  // inverse of the store swizzle for row=lane
#pragma unroll
    for (int h = 0; h < 4; ++h) {
      const float4 kA = *(const float4 *)&klds[lane][(h * 16 + 0) ^ sw];
      const float4 kB = *(const float4 *)&klds[lane][(h * 16 + 4) ^ sw];
      const float4 kC = *(const float4 *)&klds[lane][(h * 16 + 8) ^ sw];
      const float4 kD = *(const float4 *)&klds[lane][(h * 16 + 12) ^ sw];
      const float4 zA = *(const float4 *)&klds[64][h * 16 + 0];
      const float4 zB = *(const float4 *)&klds[64][h * 16 + 4];
      const float4 zC = *(const float4 *)&klds[64][h * 16 + 8];
      const float4 zD = *(const float4 *)&klds[64][h * 16 + 12];
      float l = 0.f, g = 0.f, sq;
      sq = rlane(qv, h * 16 + 0);  l += sq * kA.x; g += sq * zA.x;
      sq = rlane(qv, h * 16 + 1);  l += sq * kA.y; g += sq * zA.y;
      sq = rlane(qv, h * 16 + 2);  l += sq * kA.z; g += sq * zA.z;
      sq = rlane(qv, h * 16 + 3);  l += sq * kA.w; g += sq * zA.w;
      sq = rlane(qv, h * 16 + 4);  l += sq * kB.x; g += sq * zB.x;
      sq = rlane(qv, h * 16 + 5);  l += sq * kB.y; g += sq * zB.y;
      sq = rlane(qv, h * 16 + 6);  l += sq * kB.z; g += sq * zB.z;
      sq = rlane(qv, h * 16 + 7);  l += sq * kB.w; g += sq * zB.w;
      sq = rlane(qv, h * 16 + 8);  l += sq * kC.x; g += sq * zC.x;
      sq = rlane(qv, h * 16 + 9);  l += sq * kC.y; g += sq * zC.y;
      sq = rlane(qv, h * 16 + 10); l += sq * kC.z; g += sq * zC.z;
      sq = rlane(qv, h * 16 + 11); l += sq * kC.w; g += sq * zC.w;
      sq = rlane(qv, h * 16 + 12); l += sq * kD.x; g += sq * zD.x;
      sq = rlane(qv, h * 16 + 13); l += sq * kD.y; g += sq * zD.y;
      sq = rlane(qv, h * 16 + 14); l += sq * kD.z; g += sq * zD.z;
      sq = rlane(qv, h * 16 + 15); l += sq * kD.w; g += sq * zD.w;
      l *= 0.25f;  // 1/sqrt(dh=16)
      g *= 0.25f;
      const float mx = fmaxf(wave_max(l), g);
      const float e = __expf(l - mx);
      const float e64 = __expf(g - mx);
      const float s = wave_sum(e) + e64;
      const float inv = 1.0f / s;
      pbuf[qr][h][lane] = e * inv;
      if (lane == 0) pbuf[qr][h][64] = e64 * inv;
    }
    // ctx: lane = feature j again (same-wave LDS RAW, no barrier needed)
    const int hh = lane >> 4;
    float ca = 0.f, cb = 0.f;
    for (int m = 0; m < 64; m += 2) {
      ca += pbuf[qr][hh][m] * vlds[m][lane];
      cb += pbuf[qr][hh][m + 1] * vlds[m + 1][lane];
    }
    ca += cb + pbuf[qr][hh][64] * vlds[64][lane];
    // out = x + ctx @ Wo + bo
    float o = xself + p.bo[lane], o2 = 0.f;
    for (int c = 0; c < 64; c += 2) {
      o += rlane(ca, c) * p.Wo[c * 64 + lane];
      o2 += rlane(ca, c + 1) * p.Wo[(c + 1) * 64 + lane];
    }
    o += o2;
    // MLP
    float h1 = p.b1[lane], h1b = 0.f;
    for (int c = 0; c < 64; c += 2) {
      h1 += rlane(o, c) * p.W1[c * 64 + lane];
      h1b += rlane(o, c + 1) * p.W1[(c + 1) * 64 + lane];
    }
    h1 = fmaxf(h1 + h1b, 0.f);
    float h2 = p.b2[lane], h2b = 0.f;
    for (int c = 0; c < 64; c += 2) {
      h2 += rlane(h1, c) * p.W2[c * 64 + lane];
      h2b += rlane(h1, c + 1) * p.W2[(c + 1) * 64 + lane];
    }
    h2 = fmaxf(h2 + h2b, 0.f);
    const float tot = wave_sum(h2 * p.W3[lane]);
    if (lane == 0) p.out[b * 5 + qr] = tot + p.b3[0];
  };

  if (wid < 5) attend(q0, wid, xr[0]);
}

extern "C" void kernel_launch(void *const *d_in, const int *in_sizes, int n_in,
                              void *d_out, int out_size, void *d_ws, size_t ws_size,
                              hipStream_t stream) {
  P p;
  p.pred = (const float *)d_in[0];
  p.prey = (const float *)d_in[1];
  p.obst = (const float *)d_in[2];
  p.act  = (const float *)d_in[3];
  p.Wp = (const float *)d_in[4];  p.bp = (const float *)d_in[5];
  p.Wy = (const float *)d_in[6];  p.by = (const float *)d_in[7];
  p.Wob = (const float *)d_in[8]; p.bob = (const float *)d_in[9];
  p.Wa = (const float *)d_in[10]; p.ba = (const float *)d_in[11];
  p.Wq = (const float *)d_in[12]; p.bq = (const float *)d_in[13];
  p.Wk = (const float *)d_in[14]; p.bk = (const float *)d_in[15];
  p.Wv = (const float *)d_in[16]; p.bv = (const float *)d_in[17];
  p.Wo = (const float *)d_in[18]; p.bo = (const float *)d_in[19];
  p.W1 = (const float *)d_in[20]; p.b1 = (const float *)d_in[21];
  p.W2 = (const float *)d_in[22]; p.b2 = (const float *)d_in[23];
  p.W3 = (const float *)d_in[24]; p.b3 = (const float *)d_in[25];
  p.out = (float *)d_out;

  const int B = in_sizes[0] / 10;  // pred_state is (B, 5, 2)
  gnn_critic_kernel<<<dim3(B), dim3(512), 0, stream>>>(p);
}